// Round 5
// baseline (780.194 us; speedup 1.0000x reference)
//
#include <hip/hip_runtime.h>

typedef short short8 __attribute__((ext_vector_type(8)));
typedef float f32x4 __attribute__((ext_vector_type(4)));
typedef unsigned short us4 __attribute__((ext_vector_type(4)));

#define MFMA(a,b,c) __builtin_amdgcn_mfma_f32_16x16x32_bf16((a),(b),(c),0,0,0)

__device__ __forceinline__ unsigned short f2b(float f) {
    union { float f; unsigned int i; } v; v.f = f;
    unsigned int x = v.i;
    return (unsigned short)((x + 0x7fffu + ((x >> 16) & 1u)) >> 16);
}

// ---- weight convert+transpose: f32 [K][256] -> bf16 [256][K] ----
__global__ __launch_bounds__(256) void k_wtrans(const float* __restrict__ src,
                                                unsigned short* __restrict__ dst, int K) {
    int k = blockIdx.x, n = threadIdx.x;
    dst[(size_t)n * K + k] = f2b(src[(size_t)k * 256 + n]);
}

// ---- cls tokens into z (fp32): token 0 = cls2, token 197 = cls1 ----
__global__ __launch_bounds__(256) void k_cls(const float* __restrict__ cls1,
                                             const float* __restrict__ cls2,
                                             float* __restrict__ z) {
    int b = blockIdx.x, e = threadIdx.x;
    z[((size_t)b*394 + 0)*256 + e]   = cls2[e];
    z[((size_t)b*394 + 197)*256 + e] = cls1[e];
}

// ---- patch embed P=16 : tokens 198..393 ----
__global__ __launch_bounds__(256) void k_embed1(const float* __restrict__ x,
        const unsigned short* __restrict__ w1t, const float* __restrict__ b1,
        float* __restrict__ z) {
    __shared__ __align__(16) unsigned short A[16*776];   // 16 tokens x 768 (pad 8)
    int b = blockIdx.y, g = blockIdx.x, tid = threadIdx.x;
    for (int idx = tid; idx < 16*768; idx += 256) {
        int p = idx / 768, kk = idx - p*768;
        int j = g*16 + p;
        unsigned short v = 0;
        if (j < 196) {
            int pi = kk / 48, rem = kk - pi*48;
            int pj = rem / 3, c = rem - pj*3;
            int hi = j / 14, wi = j - hi*14;
            v = f2b(x[(((size_t)b*3 + c)*224 + hi*16 + pi)*224 + wi*16 + pj]);
        }
        A[p*776 + kk] = v;
    }
    __syncthreads();
    int wave = tid >> 6, lane = tid & 63, quad = lane >> 4, tf = lane & 15;
    f32x4 zero = {0.f,0.f,0.f,0.f};
    f32x4 acc[4] = {zero,zero,zero,zero};
    for (int ks = 0; ks < 24; ++ks) {
        short8 a = *(const short8*)&A[tf*776 + ks*32 + quad*8];
        #pragma unroll
        for (int nf = 0; nf < 4; ++nf) {
            int n = wave*64 + nf*16 + tf;
            short8 bb = *(const short8*)&w1t[(size_t)n*768 + ks*32 + quad*8];
            acc[nf] = MFMA(a, bb, acc[nf]);
        }
    }
    #pragma unroll
    for (int nf = 0; nf < 4; ++nf) {
        int n = wave*64 + nf*16 + tf;
        float bias = b1[n];
        #pragma unroll
        for (int i = 0; i < 4; ++i) {
            int j = g*16 + quad*4 + i;
            if (j < 196)
                z[((size_t)b*394 + 198 + j)*256 + n] = acc[nf][i] + bias;
        }
    }
}

// ---- patch embed P=8, sampled tokens 1..196 (patch = 4*i-1) ----
__global__ __launch_bounds__(256) void k_embed2(const float* __restrict__ x,
        const unsigned short* __restrict__ w2t, const float* __restrict__ b2,
        float* __restrict__ z) {
    __shared__ __align__(16) unsigned short A[16*200];   // 16 tokens x 192 (pad 8)
    int b = blockIdx.y, g = blockIdx.x, tid = threadIdx.x;
    for (int idx = tid; idx < 16*192; idx += 256) {
        int p = idx / 192, kk = idx - p*192;
        int it = g*16 + 1 + p;
        unsigned short v = 0;
        if (it <= 196) {
            int patch = 4*it - 1;
            int pi = kk / 24, rem = kk - pi*24;
            int pj = rem / 3, c = rem - pj*3;
            int hi = patch / 28, wi = patch - hi*28;
            v = f2b(x[(((size_t)b*3 + c)*224 + hi*8 + pi)*224 + wi*8 + pj]);
        }
        A[p*200 + kk] = v;
    }
    __syncthreads();
    int wave = tid >> 6, lane = tid & 63, quad = lane >> 4, tf = lane & 15;
    f32x4 zero = {0.f,0.f,0.f,0.f};
    f32x4 acc[4] = {zero,zero,zero,zero};
    for (int ks = 0; ks < 6; ++ks) {
        short8 a = *(const short8*)&A[tf*200 + ks*32 + quad*8];
        #pragma unroll
        for (int nf = 0; nf < 4; ++nf) {
            int n = wave*64 + nf*16 + tf;
            short8 bb = *(const short8*)&w2t[(size_t)n*192 + ks*32 + quad*8];
            acc[nf] = MFMA(a, bb, acc[nf]);
        }
    }
    #pragma unroll
    for (int nf = 0; nf < 4; ++nf) {
        int n = wave*64 + nf*16 + tf;
        float bias = b2[n];
        #pragma unroll
        for (int i = 0; i < 4; ++i) {
            int it = g*16 + 1 + quad*4 + i;
            if (it <= 196)
                z[((size_t)b*394 + it)*256 + n] = acc[nf][i] + bias;
        }
    }
}

// ---- LN1: h = bf16(LN(z)) ; one wave per token ----
__global__ __launch_bounds__(256) void k_ln1(const float* __restrict__ z,
        const float* __restrict__ gw, const float* __restrict__ bw,
        unsigned short* __restrict__ h, long ntok) {
    long t = (long)blockIdx.x*4 + (threadIdx.x >> 6);
    int lane = threadIdx.x & 63;
    if (t >= ntok) return;
    f32x4 v = *(const f32x4*)(z + (size_t)t*256 + lane*4);
    float s  = v[0]+v[1]+v[2]+v[3];
    float sq = v[0]*v[0]+v[1]*v[1]+v[2]*v[2]+v[3]*v[3];
    #pragma unroll
    for (int m = 1; m < 64; m <<= 1) { s += __shfl_xor(s, m); sq += __shfl_xor(sq, m); }
    float mean = s * (1.f/256.f);
    float rs = rsqrtf(sq*(1.f/256.f) - mean*mean + 1e-5f);
    us4 outv;
    #pragma unroll
    for (int c = 0; c < 4; ++c) {
        int e = lane*4 + c;
        outv[c] = f2b((v[c]-mean)*rs*gw[e] + bw[e]);
    }
    *(us4*)&h[(size_t)t*256 + lane*4] = outv;
}

// ---- QKV GEMM: q,k -> [bh][400][128]; v -> transposed vt [bh][128][416] ----
// rows 394..399 of q/k and cols 394..415 of vt are zero-filled (no poison in MFMA).
__global__ __launch_bounds__(256) void k_qkv(const unsigned short* __restrict__ h,
        const unsigned short* __restrict__ wqt, const unsigned short* __restrict__ wkt,
        const unsigned short* __restrict__ wvt,
        const float* __restrict__ bq, const float* __restrict__ bk,
        const float* __restrict__ bv,
        unsigned short* __restrict__ q, unsigned short* __restrict__ kbuf,
        unsigned short* __restrict__ vt) {
    __shared__ __align__(16) unsigned short A[16*264];
    int b = blockIdx.y, mt = blockIdx.x, w = blockIdx.z, tid = threadIdx.x;
    const unsigned short* wt = (w==0) ? wqt : (w==1) ? wkt : wvt;
    const float* bs = (w==0) ? bq  : (w==1) ? bk  : bv;
    for (int idx = tid; idx < 1024; idx += 256) {
        int row = idx >> 6, colb = (idx & 63) * 4;
        int n = mt*16 + row;
        us4 val = {0,0,0,0};
        if (n < 394) val = *(const us4*)&h[((size_t)b*394 + n)*256 + colb];
        *(us4*)&A[row*264 + colb] = val;
    }
    __syncthreads();
    int wave = tid>>6, lane = tid&63, quad = lane>>4, tf = lane&15;
    f32x4 zero = {0.f,0.f,0.f,0.f};
    f32x4 acc[4] = {zero,zero,zero,zero};
    for (int ks = 0; ks < 8; ++ks) {
        short8 a = *(const short8*)&A[tf*264 + ks*32 + quad*8];
        #pragma unroll
        for (int nf = 0; nf < 4; ++nf) {
            int e = wave*64 + nf*16 + tf;
            short8 bb = *(const short8*)&wt[(size_t)e*256 + ks*32 + quad*8];
            acc[nf] = MFMA(a, bb, acc[nf]);
        }
    }
    #pragma unroll
    for (int nf = 0; nf < 4; ++nf) {
        int e = wave*64 + nf*16 + tf;
        float bsv = bs[e];
        int hh = e >> 7, d = e & 127;
        #pragma unroll
        for (int i = 0; i < 4; ++i) {
            int n = mt*16 + quad*4 + i;
            unsigned short val = (n < 394) ? f2b(acc[nf][i] + bsv) : (unsigned short)0;
            if (w == 0)      q   [(((size_t)b*2 + hh)*400 + n)*128 + d] = val;
            else if (w == 1) kbuf[(((size_t)b*2 + hh)*400 + n)*128 + d] = val;
            else             vt  [(((size_t)b*2 + hh)*128 + d)*416 + n] = val;
        }
    }
    if (w == 2 && mt == 24) {   // zero vt pad cols 400..415
        for (int t = tid; t < 4096; t += 256) {
            int hh2 = t >> 11, d2 = (t >> 4) & 127, c = t & 15;
            vt[(((size_t)b*2 + hh2)*128 + d2)*416 + 400 + c] = 0;
        }
    }
}

// ---- fused attention: QK^T -> softmax -> (P in LDS) -> PV ; one wave per 16 q-rows ----
__global__ __launch_bounds__(64) void k_att(const unsigned short* __restrict__ q,
        const unsigned short* __restrict__ kbuf, const unsigned short* __restrict__ vt,
        unsigned short* __restrict__ o) {
    __shared__ __align__(16) unsigned short Pl[16*416];
    int mt = blockIdx.x, bh = blockIdx.y;
    int lane = threadIdx.x, quad = lane>>4, tf = lane&15;
    const unsigned short* qp = q    + (size_t)bh*51200;
    const unsigned short* kp = kbuf + (size_t)bh*51200;
    short8 afr[4];
    #pragma unroll
    for (int ks = 0; ks < 4; ++ks)
        afr[ks] = *(const short8*)&qp[(size_t)(mt*16 + tf)*128 + ks*32 + quad*8];
    f32x4 zero = {0.f,0.f,0.f,0.f};
    f32x4 acc[25];
    #pragma unroll
    for (int nf = 0; nf < 25; ++nf) acc[nf] = zero;
    #pragma unroll
    for (int nf = 0; nf < 25; ++nf) {
        #pragma unroll
        for (int ks = 0; ks < 4; ++ks) {
            short8 bb = *(const short8*)&kp[(size_t)(nf*16 + tf)*128 + ks*32 + quad*8];
            acc[nf] = MFMA(afr[ks], bb, acc[nf]);
        }
    }
    #pragma unroll
    for (int i = 0; i < 4; ++i) {
        int row = quad*4 + i;
        float mx = -3e38f;
        #pragma unroll
        for (int nf = 0; nf < 25; ++nf)
            if (nf < 24 || tf < 10) mx = fmaxf(mx, acc[nf][i]);
        #pragma unroll
        for (int m = 1; m < 16; m <<= 1) mx = fmaxf(mx, __shfl_xor(mx, m));
        float s = 0.f;
        #pragma unroll
        for (int nf = 0; nf < 25; ++nf)
            if (nf < 24 || tf < 10) s += __expf(acc[nf][i] - mx);
        #pragma unroll
        for (int m = 1; m < 16; m <<= 1) s += __shfl_xor(s, m);
        float inv = 1.f / (16.f * s);      // softmax then /sqrt(EMB)=16
        #pragma unroll
        for (int nf = 0; nf < 25; ++nf) {
            float p = (nf < 24 || tf < 10) ? __expf(acc[nf][i] - mx) * inv : 0.f;
            Pl[row*416 + nf*16 + tf] = f2b(p);
        }
        Pl[row*416 + 400 + tf] = 0;   // zero K-pad cols 400..415
    }
    __syncthreads();
    const unsigned short* vp = vt + (size_t)bh*53248;
    f32x4 acc2[8];
    #pragma unroll
    for (int nf = 0; nf < 8; ++nf) acc2[nf] = zero;
    for (int ks = 0; ks < 13; ++ks) {
        short8 a = *(const short8*)&Pl[tf*416 + ks*32 + quad*8];
        #pragma unroll
        for (int nf = 0; nf < 8; ++nf) {
            short8 bb = *(const short8*)&vp[(size_t)(nf*16 + tf)*416 + ks*32 + quad*8];
            acc2[nf] = MFMA(a, bb, acc2[nf]);
        }
    }
    int b = bh >> 1, hh = bh & 1;
    #pragma unroll
    for (int nf = 0; nf < 8; ++nf) {
        int e = hh*128 + nf*16 + tf;
        #pragma unroll
        for (int i = 0; i < 4; ++i) {
            int n = mt*16 + quad*4 + i;
            if (n < 394)
                o[((size_t)b*394 + n)*256 + e] = f2b(acc2[nf][i]);
        }
    }
}

// ---- proj GEMM + LN2 + residual into z (fp32) ----
__global__ __launch_bounds__(256) void k_proj(const unsigned short* __restrict__ o,
        const unsigned short* __restrict__ wpt, const float* __restrict__ bp,
        const float* __restrict__ g2, const float* __restrict__ bb2,
        float* __restrict__ z) {
    __shared__ __align__(16) float S[16*260];
    int mt = blockIdx.x, b = blockIdx.y, tid = threadIdx.x;
    int wave = tid>>6, lane = tid&63, quad = lane>>4, tf = lane&15;
    f32x4 zero = {0.f,0.f,0.f,0.f};
    f32x4 acc[4] = {zero,zero,zero,zero};
    int arow = mt*16 + tf; if (arow > 393) arow = 393;   // clamp: garbage rows discarded
    for (int ks = 0; ks < 8; ++ks) {
        short8 a = *(const short8*)&o[((size_t)b*394 + arow)*256 + ks*32 + quad*8];
        #pragma unroll
        for (int nf = 0; nf < 4; ++nf) {
            int e = wave*64 + nf*16 + tf;
            short8 bbv = *(const short8*)&wpt[(size_t)e*256 + ks*32 + quad*8];
            acc[nf] = MFMA(a, bbv, acc[nf]);
        }
    }
    #pragma unroll
    for (int nf = 0; nf < 4; ++nf) {
        int e = wave*64 + nf*16 + tf;
        float bsv = bp[e];
        #pragma unroll
        for (int i = 0; i < 4; ++i)
            S[(quad*4 + i)*260 + e] = acc[nf][i] + bsv;
    }
    __syncthreads();
    #pragma unroll
    for (int rr = 0; rr < 4; ++rr) {
        int row = wave*4 + rr;
        f32x4 v = *(const f32x4*)&S[row*260 + lane*4];
        float s  = v[0]+v[1]+v[2]+v[3];
        float sq = v[0]*v[0]+v[1]*v[1]+v[2]*v[2]+v[3]*v[3];
        #pragma unroll
        for (int m = 1; m < 64; m <<= 1) { s += __shfl_xor(s, m); sq += __shfl_xor(sq, m); }
        float mean = s*(1.f/256.f);
        float rs = rsqrtf(sq*(1.f/256.f) - mean*mean + 1e-5f);
        int n = mt*16 + row;
        if (n < 394) {
            float* zr = z + ((size_t)b*394 + n)*256 + lane*4;
            f32x4 zv = *(f32x4*)zr;
            #pragma unroll
            for (int c = 0; c < 4; ++c) {
                int e = lane*4 + c;
                zv[c] += (v[c]-mean)*rs*g2[e] + bb2[e];
            }
            *(f32x4*)zr = zv;
        }
    }
}

// ---- mean-pool + LNc + classifier + log_softmax -> FLOAT32 out ----
__global__ __launch_bounds__(256) void k_pool(const float* __restrict__ z,
        const float* __restrict__ lg, const float* __restrict__ lb,
        const float* __restrict__ wc, const float* __restrict__ bc,
        float* __restrict__ out) {
    __shared__ float red[8];
    int b = blockIdx.x, e = threadIdx.x;
    int wave = e>>6, lane = e&63;
    const float* zp = z + (size_t)b*394*256 + e;
    float s = 0.f;
    for (int n = 0; n < 394; ++n) s += zp[(size_t)n*256];
    float pooled = s * (1.f/394.f);
    float a = pooled, sq = pooled*pooled;
    #pragma unroll
    for (int m = 1; m < 64; m <<= 1) { a += __shfl_xor(a, m); sq += __shfl_xor(sq, m); }
    if (lane == 0) { red[wave] = a; red[4+wave] = sq; }
    __syncthreads();
    float tot  = red[0]+red[1]+red[2]+red[3];
    float totq = red[4]+red[5]+red[6]+red[7];
    float mean = tot*(1.f/256.f);
    float rs = rsqrtf(totq*(1.f/256.f) - mean*mean + 1e-5f);
    float ln = (pooled-mean)*rs*lg[e] + lb[e];
    float t0 = ln * wc[e*2];
    float t1 = ln * wc[e*2+1];
    #pragma unroll
    for (int m = 1; m < 64; m <<= 1) { t0 += __shfl_xor(t0, m); t1 += __shfl_xor(t1, m); }
    __syncthreads();
    if (lane == 0) { red[wave] = t0; red[4+wave] = t1; }
    __syncthreads();
    if (e < 2) {
        float l0 = red[0]+red[1]+red[2]+red[3] + bc[0];
        float l1 = red[4]+red[5]+red[6]+red[7] + bc[1];
        float mx = fmaxf(l0, l1);
        float lse = mx + logf(__expf(l0-mx) + __expf(l1-mx));
        out[b*2 + e] = (e==0 ? l0 : l1) - lse;
    }
}

extern "C" void kernel_launch(void* const* d_in, const int* in_sizes, int n_in,
                              void* d_out, int out_size, void* d_ws, size_t ws_size,
                              hipStream_t stream) {
    typedef unsigned short u16;
    const float* x    = (const float*)d_in[0];
    const float* W1   = (const float*)d_in[1];
    const float* b1   = (const float*)d_in[2];
    const float* cls1 = (const float*)d_in[3];
    const float* W2   = (const float*)d_in[4];
    const float* b2   = (const float*)d_in[5];
    const float* cls2 = (const float*)d_in[6];
    const float* ln1g = (const float*)d_in[7];
    const float* ln1b = (const float*)d_in[8];
    const float* Wq   = (const float*)d_in[9];
    const float* bq   = (const float*)d_in[10];
    const float* Wk   = (const float*)d_in[11];
    const float* bk   = (const float*)d_in[12];
    const float* Wv   = (const float*)d_in[13];
    const float* bv   = (const float*)d_in[14];
    const float* Wp   = (const float*)d_in[15];
    const float* bp   = (const float*)d_in[16];
    const float* ln2g = (const float*)d_in[17];
    const float* ln2b = (const float*)d_in[18];
    const float* lncg = (const float*)d_in[19];
    const float* lncb = (const float*)d_in[20];
    const float* Wc   = (const float*)d_in[21];
    const float* bcp  = (const float*)d_in[22];

    int Bn = in_sizes[0] / (3*224*224);

    // workspace layout: [weights 1,015,808 B][z fp32][h][q][kb][vt][o], chunked over batch
    const size_t WBYTES = 1015808;
    const size_t PER_IMG = 403456 + 201728 + 204800 + 204800 + 212992 + 201728; // 1,429,504 B

    int Bc = (Bn < 128) ? Bn : 128;
    while (Bc > 1 && WBYTES + (size_t)Bc * PER_IMG > ws_size) Bc >>= 1;

    u16* w1t = (u16*)d_ws;            // [256][768]
    u16* w2t = w1t + 196608;          // [256][192]
    u16* wqt = w2t + 49152;           // [256][256]
    u16* wkt = wqt + 65536;
    u16* wvt = wkt + 65536;
    u16* wpt = wvt + 65536;
    float* z = (float*)(wpt + 65536);                 // [Bc][394][256] fp32
    u16* h   = (u16*)(z + (size_t)Bc*100864);         // [Bc][394][256]
    u16* q   = h + (size_t)Bc*100864;                 // [Bc*2][400][128]
    u16* kb  = q + (size_t)Bc*102400;
    u16* vt  = kb + (size_t)Bc*102400;                // [Bc*2][128][416]
    u16* o   = vt + (size_t)Bc*106496;                // [Bc][394][256]

    k_wtrans<<<768, 256, 0, stream>>>(W1, w1t, 768);
    k_wtrans<<<192, 256, 0, stream>>>(W2, w2t, 192);
    k_wtrans<<<256, 256, 0, stream>>>(Wq, wqt, 256);
    k_wtrans<<<256, 256, 0, stream>>>(Wk, wkt, 256);
    k_wtrans<<<256, 256, 0, stream>>>(Wv, wvt, 256);
    k_wtrans<<<256, 256, 0, stream>>>(Wp, wpt, 256);

    for (int b0 = 0; b0 < Bn; b0 += Bc) {
        int bc = (Bn - b0 < Bc) ? (Bn - b0) : Bc;
        const float* xb = x + (size_t)b0 * 3*224*224;
        float* outb = (float*)d_out + (size_t)b0 * 2;
        size_t ntok = (size_t)bc * 394;

        k_cls<<<bc, 256, 0, stream>>>(cls1, cls2, z);
        k_embed1<<<dim3(13, bc), 256, 0, stream>>>(xb, w1t, b1, z);
        k_embed2<<<dim3(13, bc), 256, 0, stream>>>(xb, w2t, b2, z);
        k_ln1<<<(unsigned)((ntok + 3)/4), 256, 0, stream>>>(z, ln1g, ln1b, h, (long)ntok);
        k_qkv<<<dim3(25, bc, 3), 256, 0, stream>>>(h, wqt, wkt, wvt, bq, bk, bv, q, kb, vt);
        k_att<<<dim3(25, bc*2), 64, 0, stream>>>(q, kb, vt, o);
        k_proj<<<dim3(25, bc), 256, 0, stream>>>(o, wpt, bp, ln2g, ln2b, z);
        k_pool<<<bc, 256, 0, stream>>>(z, lncg, lncb, Wc, bcp, outb);
    }
}

// Round 7
// 571.700 us; speedup vs baseline: 1.3647x; 1.3647x over previous
//
#include <hip/hip_runtime.h>

typedef short short8 __attribute__((ext_vector_type(8)));
typedef float f32x4 __attribute__((ext_vector_type(4)));
typedef unsigned short us4 __attribute__((ext_vector_type(4)));
typedef unsigned short u16;

#define MFMA(a,b,c) __builtin_amdgcn_mfma_f32_16x16x32_bf16((a),(b),(c),0,0,0)

__device__ __forceinline__ u16 f2b(float f) {
    union { float f; unsigned int i; } v; v.f = f;
    unsigned int x = v.i;
    return (u16)((x + 0x7fffu + ((x >> 16) & 1u)) >> 16);
}

// ---- all weights -> bf16 transposed; W1/W2 additionally permuted to channel-planar k' ----
// W1: k = pi*48+pj*3+c  ->  k' = c*256+pi*16+pj      W2: k = pi*24+pj*3+c -> k' = c*64+pi*8+pj
__global__ __launch_bounds__(256) void k_wtrans(const float* __restrict__ W1,
        const float* __restrict__ W2, const float* __restrict__ Wq, const float* __restrict__ Wk,
        const float* __restrict__ Wv, const float* __restrict__ Wp,
        u16* __restrict__ w1t, u16* __restrict__ w2t, u16* __restrict__ wqt,
        u16* __restrict__ wkt, u16* __restrict__ wvt, u16* __restrict__ wpt) {
    int bx = blockIdx.x, n = threadIdx.x;
    if (bx < 768) {
        int k = bx, c = k % 3, t = k / 3, pj = t & 15, pi = t >> 4;
        w1t[(size_t)n*768 + c*256 + pi*16 + pj] = f2b(W1[(size_t)k*256 + n]);
    } else if (bx < 960) {
        int k = bx - 768, c = k % 3, t = k / 3, pj = t & 7, pi = t >> 3;
        w2t[(size_t)n*192 + c*64 + pi*8 + pj] = f2b(W2[(size_t)k*256 + n]);
    } else if (bx < 1216) { int k = bx - 960;  wqt[(size_t)n*256 + k] = f2b(Wq[(size_t)k*256 + n]); }
    else if (bx < 1472)   { int k = bx - 1216; wkt[(size_t)n*256 + k] = f2b(Wk[(size_t)k*256 + n]); }
    else if (bx < 1728)   { int k = bx - 1472; wvt[(size_t)n*256 + k] = f2b(Wv[(size_t)k*256 + n]); }
    else                  { int k = bx - 1728; wpt[(size_t)n*256 + k] = f2b(Wp[(size_t)k*256 + n]); }
}

// ---- cls tokens (0 = cls2, 197 = cls1) into z, fused LN1 -> h ----
__global__ __launch_bounds__(256) void k_cls(const float* __restrict__ cls1,
        const float* __restrict__ cls2, const float* __restrict__ g1, const float* __restrict__ be1,
        float* __restrict__ z, u16* __restrict__ h) {
    __shared__ float red[16];
    int b = blockIdx.x, e = threadIdx.x, lane = e & 63, w = e >> 6;
    float v0 = cls2[e], v1 = cls1[e];
    z[((size_t)b*394 + 0)*256 + e]   = v0;
    z[((size_t)b*394 + 197)*256 + e] = v1;
    float s0 = v0, q0 = v0*v0, s1 = v1, q1 = v1*v1;
    #pragma unroll
    for (int m = 1; m < 64; m <<= 1) {
        s0 += __shfl_xor(s0, m); q0 += __shfl_xor(q0, m);
        s1 += __shfl_xor(s1, m); q1 += __shfl_xor(q1, m);
    }
    if (lane == 0) { red[w] = s0; red[4+w] = q0; red[8+w] = s1; red[12+w] = q1; }
    __syncthreads();
    float S0 = red[0]+red[1]+red[2]+red[3],   Q0 = red[4]+red[5]+red[6]+red[7];
    float S1 = red[8]+red[9]+red[10]+red[11], Q1 = red[12]+red[13]+red[14]+red[15];
    float m0 = S0*(1.f/256.f), r0 = rsqrtf(Q0*(1.f/256.f) - m0*m0 + 1e-5f);
    float m1 = S1*(1.f/256.f), r1 = rsqrtf(Q1*(1.f/256.f) - m1*m1 + 1e-5f);
    h[((size_t)b*394 + 0)*256 + e]   = f2b((v0-m0)*r0*g1[e] + be1[e]);
    h[((size_t)b*394 + 197)*256 + e] = f2b((v1-m1)*r1*g1[e] + be1[e]);
}

// ---- patch embed P=16 (tokens 198..393) + fused LN1 ----
__global__ __launch_bounds__(256) void k_embed1(const float* __restrict__ x,
        const u16* __restrict__ w1t, const float* __restrict__ b1,
        const float* __restrict__ g1, const float* __restrict__ be1,
        float* __restrict__ z, u16* __restrict__ h) {
    __shared__ __align__(16) u16 A[16*776];
    __shared__ __align__(16) float S[16*260];
    int b = blockIdx.y, g = blockIdx.x, tid = threadIdx.x;
    int p = tid >> 4, pi = tid & 15;
    int j = g*16 + p;
    if (j < 196) {
        int hi = j / 14, wi = j - hi*14;
        #pragma unroll
        for (int c = 0; c < 3; ++c) {
            const float* src = x + (((size_t)b*3 + c)*224 + hi*16 + pi)*224 + wi*16;
            #pragma unroll
            for (int s4 = 0; s4 < 4; ++s4) {
                f32x4 r = *(const f32x4*)(src + s4*4);
                us4 o; o[0] = f2b(r[0]); o[1] = f2b(r[1]); o[2] = f2b(r[2]); o[3] = f2b(r[3]);
                *(us4*)&A[p*776 + c*256 + pi*16 + s4*4] = o;
            }
        }
    } else {
        us4 zer = {0,0,0,0};
        #pragma unroll
        for (int c = 0; c < 3; ++c)
            #pragma unroll
            for (int s4 = 0; s4 < 4; ++s4)
                *(us4*)&A[p*776 + c*256 + pi*16 + s4*4] = zer;
    }
    __syncthreads();
    int w = tid >> 6, lane = tid & 63, quad = lane >> 4, tf = lane & 15;
    f32x4 zero = {0.f,0.f,0.f,0.f};
    f32x4 acc[4] = {zero,zero,zero,zero};
    for (int ks = 0; ks < 24; ++ks) {
        short8 a = *(const short8*)&A[tf*776 + ks*32 + quad*8];
        #pragma unroll
        for (int nf = 0; nf < 4; ++nf) {
            int n = w*64 + nf*16 + tf;
            short8 bb = *(const short8*)&w1t[(size_t)n*768 + ks*32 + quad*8];
            acc[nf] = MFMA(a, bb, acc[nf]);
        }
    }
    #pragma unroll
    for (int nf = 0; nf < 4; ++nf) {
        int n = w*64 + nf*16 + tf;
        float bias = b1[n];
        #pragma unroll
        for (int i = 0; i < 4; ++i)
            S[(quad*4 + i)*260 + n] = acc[nf][i] + bias;
    }
    __syncthreads();
    #pragma unroll
    for (int rr = 0; rr < 4; ++rr) {
        int row = w*4 + rr;
        int j2 = g*16 + row;
        f32x4 v = *(const f32x4*)&S[row*260 + lane*4];
        float s = v[0]+v[1]+v[2]+v[3];
        float sq = v[0]*v[0]+v[1]*v[1]+v[2]*v[2]+v[3]*v[3];
        #pragma unroll
        for (int m = 1; m < 64; m <<= 1) { s += __shfl_xor(s, m); sq += __shfl_xor(sq, m); }
        float mean = s*(1.f/256.f);
        float rs = rsqrtf(sq*(1.f/256.f) - mean*mean + 1e-5f);
        if (j2 < 196) {
            size_t base = ((size_t)b*394 + 198 + j2)*256 + lane*4;
            *(f32x4*)&z[base] = v;
            us4 ho;
            #pragma unroll
            for (int c = 0; c < 4; ++c) {
                int e = lane*4 + c;
                ho[c] = f2b((v[c]-mean)*rs*g1[e] + be1[e]);
            }
            *(us4*)&h[base] = ho;
        }
    }
}

// ---- patch embed P=8 sampled (tokens 1..196, patch=4*it-1) + fused LN1 ----
__global__ __launch_bounds__(256) void k_embed2(const float* __restrict__ x,
        const u16* __restrict__ w2t, const float* __restrict__ b2,
        const float* __restrict__ g1, const float* __restrict__ be1,
        float* __restrict__ z, u16* __restrict__ h) {
    __shared__ __align__(16) u16 A[16*200];
    __shared__ __align__(16) float S[16*260];
    int b = blockIdx.y, g = blockIdx.x, tid = threadIdx.x;
    int p = tid >> 4, s16 = tid & 15;
    int pi = s16 >> 1, ph = s16 & 1;
    int it = g*16 + p + 1;
    if (it <= 196) {
        int patch = 4*it - 1;
        int hi = patch / 28, wi = patch - hi*28;
        #pragma unroll
        for (int c = 0; c < 3; ++c) {
            const float* src = x + (((size_t)b*3 + c)*224 + hi*8 + pi)*224 + wi*8 + ph*4;
            f32x4 r = *(const f32x4*)src;
            us4 o; o[0] = f2b(r[0]); o[1] = f2b(r[1]); o[2] = f2b(r[2]); o[3] = f2b(r[3]);
            *(us4*)&A[p*200 + c*64 + pi*8 + ph*4] = o;
        }
    } else {
        us4 zer = {0,0,0,0};
        #pragma unroll
        for (int c = 0; c < 3; ++c)
            *(us4*)&A[p*200 + c*64 + pi*8 + ph*4] = zer;
    }
    __syncthreads();
    int w = tid >> 6, lane = tid & 63, quad = lane >> 4, tf = lane & 15;
    f32x4 zero = {0.f,0.f,0.f,0.f};
    f32x4 acc[4] = {zero,zero,zero,zero};
    for (int ks = 0; ks < 6; ++ks) {
        short8 a = *(const short8*)&A[tf*200 + ks*32 + quad*8];
        #pragma unroll
        for (int nf = 0; nf < 4; ++nf) {
            int n = w*64 + nf*16 + tf;
            short8 bb = *(const short8*)&w2t[(size_t)n*192 + ks*32 + quad*8];
            acc[nf] = MFMA(a, bb, acc[nf]);
        }
    }
    #pragma unroll
    for (int nf = 0; nf < 4; ++nf) {
        int n = w*64 + nf*16 + tf;
        float bias = b2[n];
        #pragma unroll
        for (int i = 0; i < 4; ++i)
            S[(quad*4 + i)*260 + n] = acc[nf][i] + bias;
    }
    __syncthreads();
    #pragma unroll
    for (int rr = 0; rr < 4; ++rr) {
        int row = w*4 + rr;
        int it2 = g*16 + row + 1;
        f32x4 v = *(const f32x4*)&S[row*260 + lane*4];
        float s = v[0]+v[1]+v[2]+v[3];
        float sq = v[0]*v[0]+v[1]*v[1]+v[2]*v[2]+v[3]*v[3];
        #pragma unroll
        for (int m = 1; m < 64; m <<= 1) { s += __shfl_xor(s, m); sq += __shfl_xor(sq, m); }
        float mean = s*(1.f/256.f);
        float rs = rsqrtf(sq*(1.f/256.f) - mean*mean + 1e-5f);
        if (it2 <= 196) {
            size_t base = ((size_t)b*394 + it2)*256 + lane*4;
            *(f32x4*)&z[base] = v;
            us4 ho;
            #pragma unroll
            for (int c = 0; c < 4; ++c) {
                int e = lane*4 + c;
                ho[c] = f2b((v[c]-mean)*rs*g1[e] + be1[e]);
            }
            *(us4*)&h[base] = ho;
        }
    }
}

// ---- fused QKV GEMM, M=32: q,k -> [bh][416][128]; v -> vt [bh][128][416] ----
// all pad rows/cols (n>=394) written as zeros.
__global__ __launch_bounds__(256) void k_qkv(const u16* __restrict__ h,
        const u16* __restrict__ wqt, const u16* __restrict__ wkt, const u16* __restrict__ wvt,
        const float* __restrict__ bq, const float* __restrict__ bk, const float* __restrict__ bv,
        u16* __restrict__ q, u16* __restrict__ kb, u16* __restrict__ vt) {
    __shared__ __align__(16) u16 A[32*264];
    int mt = blockIdx.x, b = blockIdx.y, tid = threadIdx.x;
    for (int idx = tid; idx < 2048; idx += 256) {
        int row = idx >> 6, col4 = (idx & 63) * 4;
        int n = mt*32 + row;
        us4 val = {0,0,0,0};
        if (n < 394) val = *(const us4*)&h[((size_t)b*394 + n)*256 + col4];
        *(us4*)&A[row*264 + col4] = val;
    }
    __syncthreads();
    int w = tid >> 6, lane = tid & 63, quad = lane >> 4, tf = lane & 15;
    f32x4 zero = {0.f,0.f,0.f,0.f};
    f32x4 aq[2][4], ak[2][4], av[2][4];
    #pragma unroll
    for (int m = 0; m < 2; ++m)
        #pragma unroll
        for (int nf = 0; nf < 4; ++nf) { aq[m][nf] = zero; ak[m][nf] = zero; av[m][nf] = zero; }
    for (int ks = 0; ks < 8; ++ks) {
        short8 a0 = *(const short8*)&A[tf*264 + ks*32 + quad*8];
        short8 a1 = *(const short8*)&A[(16+tf)*264 + ks*32 + quad*8];
        #pragma unroll
        for (int nf = 0; nf < 4; ++nf) {
            size_t off = (size_t)(w*64 + nf*16 + tf)*256 + ks*32 + quad*8;
            short8 bwq = *(const short8*)&wqt[off];
            aq[0][nf] = MFMA(a0, bwq, aq[0][nf]);
            aq[1][nf] = MFMA(a1, bwq, aq[1][nf]);
            short8 bwk = *(const short8*)&wkt[off];
            ak[0][nf] = MFMA(a0, bwk, ak[0][nf]);
            ak[1][nf] = MFMA(a1, bwk, ak[1][nf]);
            short8 bwv = *(const short8*)&wvt[off];
            av[0][nf] = MFMA(a0, bwv, av[0][nf]);
            av[1][nf] = MFMA(a1, bwv, av[1][nf]);
        }
    }
    #pragma unroll
    for (int nf = 0; nf < 4; ++nf) {
        int e = w*64 + nf*16 + tf;
        int hh = e >> 7, d = e & 127;
        size_t bh = (size_t)b*2 + hh;
        float vq = bq[e], vk = bk[e], vv = bv[e];
        #pragma unroll
        for (int m = 0; m < 2; ++m)
            #pragma unroll
            for (int i = 0; i < 4; ++i) {
                int n = mt*32 + m*16 + quad*4 + i;
                u16 q_v = (n < 394) ? f2b(aq[m][nf][i] + vq) : (u16)0;
                u16 k_v = (n < 394) ? f2b(ak[m][nf][i] + vk) : (u16)0;
                u16 v_v = (n < 394) ? f2b(av[m][nf][i] + vv) : (u16)0;
                q [(bh*416 + n)*128 + d] = q_v;
                kb[(bh*416 + n)*128 + d] = k_v;
                vt[(bh*128 + d)*416 + n] = v_v;
            }
    }
}

// ---- attention: 4 waves/block, 64 q-rows, LDS-shared K/V tiles ----
__global__ __launch_bounds__(256) void k_att(const u16* __restrict__ q,
        const u16* __restrict__ kbuf, const u16* __restrict__ vt, u16* __restrict__ o) {
    __shared__ __align__(16) u16 Pl[4*16*424];   // 54,272 B
    __shared__ __align__(16) u16 Stage[5120];    // 10,240 B (K: 32x136, V: 128x40)
    int bx = blockIdx.x, bh = blockIdx.y, tid = threadIdx.x;
    int w = tid >> 6, lane = tid & 63, quad = lane >> 4, tf = lane & 15;
    int mt_raw = bx*4 + w;
    int mt = mt_raw < 26 ? mt_raw : 25;
    const u16* qp = q    + (size_t)bh*53248;
    const u16* kp = kbuf + (size_t)bh*53248;
    const u16* vp = vt   + (size_t)bh*53248;
    short8 afr[4];
    #pragma unroll
    for (int ks = 0; ks < 4; ++ks)
        afr[ks] = *(const short8*)&qp[(size_t)(mt*16 + tf)*128 + ks*32 + quad*8];
    f32x4 zero = {0.f,0.f,0.f,0.f};
    f32x4 acc[26];
    #pragma unroll
    for (int nt = 0; nt < 26; ++nt) acc[nt] = zero;
    // phase 1: QK^T over 13 K-chunks of 32 rows (K chunk: 32 rows x 128, stride 136)
    for (int kc = 0; kc < 13; ++kc) {
        for (int i = tid; i < 512; i += 256) {
            int r = i >> 4, seg = i & 15;
            uint4 vsrc = *(const uint4*)&kp[(size_t)(kc*32 + r)*128 + seg*8];
            *(uint4*)&Stage[r*136 + seg*8] = vsrc;
        }
        __syncthreads();
        #pragma unroll
        for (int ncl = 0; ncl < 2; ++ncl) {
            int nt = kc*2 + ncl;
            #pragma unroll
            for (int ks = 0; ks < 4; ++ks) {
                short8 bb = *(const short8*)&Stage[(ncl*16 + tf)*136 + ks*32 + quad*8];
                acc[nt] = MFMA(afr[ks], bb, acc[nt]);
            }
        }
        __syncthreads();
    }
    // phase 2: softmax (valid cols: nt<24 fully, nt==24 tf<10)
    u16* myP = Pl + w*16*424;
    #pragma unroll
    for (int i = 0; i < 4; ++i) {
        int row = quad*4 + i;
        float mx = -3e38f;
        #pragma unroll
        for (int nt = 0; nt < 26; ++nt)
            if (nt < 24 || (nt == 24 && tf < 10)) mx = fmaxf(mx, acc[nt][i]);
        #pragma unroll
        for (int m = 1; m < 16; m <<= 1) mx = fmaxf(mx, __shfl_xor(mx, m));
        float s = 0.f;
        #pragma unroll
        for (int nt = 0; nt < 26; ++nt)
            if (nt < 24 || (nt == 24 && tf < 10)) s += __expf(acc[nt][i] - mx);
        #pragma unroll
        for (int m = 1; m < 16; m <<= 1) s += __shfl_xor(s, m);
        float inv = 1.f / (16.f * s);
        #pragma unroll
        for (int nt = 0; nt < 26; ++nt) {
            float p = (nt < 24 || (nt == 24 && tf < 10)) ? __expf(acc[nt][i] - mx) * inv : 0.f;
            myP[row*424 + nt*16 + tf] = f2b(p);
        }
    }
    __syncthreads();
    // phase 3: PV over 13 V-chunks of 32 cols (V chunk: 128 rows(d) x 32, stride 40)
    f32x4 acc2[8];
    #pragma unroll
    for (int nf = 0; nf < 8; ++nf) acc2[nf] = zero;
    for (int kc = 0; kc < 13; ++kc) {
        for (int i = tid; i < 512; i += 256) {
            int d = i >> 2, seg = i & 3;                 // FIXED: 128 rows x 4 segs of 8 u16
            uint4 vsrc = *(const uint4*)&vp[(size_t)d*416 + kc*32 + seg*8];
            *(uint4*)&Stage[d*40 + seg*8] = vsrc;
        }
        __syncthreads();
        short8 a = *(const short8*)&myP[tf*424 + kc*32 + quad*8];
        #pragma unroll
        for (int nf = 0; nf < 8; ++nf) {
            short8 bb = *(const short8*)&Stage[(nf*16 + tf)*40 + quad*8];
            acc2[nf] = MFMA(a, bb, acc2[nf]);
        }
        __syncthreads();
    }
    int b = bh >> 1, hh = bh & 1;
    if (mt_raw < 26) {
        #pragma unroll
        for (int nf = 0; nf < 8; ++nf) {
            int e = hh*128 + nf*16 + tf;
            #pragma unroll
            for (int i = 0; i < 4; ++i) {
                int n = mt_raw*16 + quad*4 + i;
                if (n < 394)
                    o[((size_t)b*394 + n)*256 + e] = f2b(acc2[nf][i]);
            }
        }
    }
}

// ---- proj GEMM (M=32) + LN2 + residual into z ----
__global__ __launch_bounds__(256) void k_proj(const u16* __restrict__ o,
        const u16* __restrict__ wpt, const float* __restrict__ bp,
        const float* __restrict__ g2, const float* __restrict__ bb2,
        float* __restrict__ z) {
    __shared__ __align__(16) u16 A[32*264];
    __shared__ __align__(16) float S[32*260];
    int mt = blockIdx.x, b = blockIdx.y, tid = threadIdx.x;
    int w = tid >> 6, lane = tid & 63, quad = lane >> 4, tf = lane & 15;
    for (int idx = tid; idx < 2048; idx += 256) {
        int row = idx >> 6, col4 = (idx & 63) * 4;
        int n = mt*32 + row;
        us4 val = {0,0,0,0};
        if (n < 394) val = *(const us4*)&o[((size_t)b*394 + n)*256 + col4];
        *(us4*)&A[row*264 + col4] = val;
    }
    __syncthreads();
    f32x4 zero = {0.f,0.f,0.f,0.f};
    f32x4 acc[2][4];
    #pragma unroll
    for (int m = 0; m < 2; ++m)
        #pragma unroll
        for (int nf = 0; nf < 4; ++nf) acc[m][nf] = zero;
    for (int ks = 0; ks < 8; ++ks) {
        short8 a0 = *(const short8*)&A[tf*264 + ks*32 + quad*8];
        short8 a1 = *(const short8*)&A[(16+tf)*264 + ks*32 + quad*8];
        #pragma unroll
        for (int nf = 0; nf < 4; ++nf) {
            short8 bb = *(const short8*)&wpt[(size_t)(w*64 + nf*16 + tf)*256 + ks*32 + quad*8];
            acc[0][nf] = MFMA(a0, bb, acc[0][nf]);
            acc[1][nf] = MFMA(a1, bb, acc[1][nf]);
        }
    }
    #pragma unroll
    for (int nf = 0; nf < 4; ++nf) {
        int e = w*64 + nf*16 + tf;
        float bsv = bp[e];
        #pragma unroll
        for (int m = 0; m < 2; ++m)
            #pragma unroll
            for (int i = 0; i < 4; ++i)
                S[(m*16 + quad*4 + i)*260 + e] = acc[m][nf][i] + bsv;
    }
    __syncthreads();
    #pragma unroll
    for (int rr = 0; rr < 8; ++rr) {
        int row = w*8 + rr;
        f32x4 v = *(const f32x4*)&S[row*260 + lane*4];
        float s = v[0]+v[1]+v[2]+v[3];
        float sq = v[0]*v[0]+v[1]*v[1]+v[2]*v[2]+v[3]*v[3];
        #pragma unroll
        for (int m = 1; m < 64; m <<= 1) { s += __shfl_xor(s, m); sq += __shfl_xor(sq, m); }
        float mean = s*(1.f/256.f);
        float rs = rsqrtf(sq*(1.f/256.f) - mean*mean + 1e-5f);
        int n = mt*32 + row;
        if (n < 394) {
            float* zr = z + ((size_t)b*394 + n)*256 + lane*4;
            f32x4 zv = *(f32x4*)zr;
            #pragma unroll
            for (int c = 0; c < 4; ++c) {
                int e = lane*4 + c;
                zv[c] += (v[c]-mean)*rs*g2[e] + bb2[e];
            }
            *(f32x4*)zr = zv;
        }
    }
}

// ---- mean-pool + LNc + classifier + log_softmax (f32 out) ----
__global__ __launch_bounds__(256) void k_pool(const float* __restrict__ z,
        const float* __restrict__ lg, const float* __restrict__ lb,
        const float* __restrict__ wc, const float* __restrict__ bc,
        float* __restrict__ out) {
    __shared__ float red[8];
    int b = blockIdx.x, e = threadIdx.x;
    int wave = e >> 6, lane = e & 63;
    const float* zp = z + (size_t)b*394*256 + e;
    float p0 = 0.f, p1 = 0.f, p2 = 0.f, p3 = 0.f;
    int n = 0;
    for (; n + 3 < 394; n += 4) {
        p0 += zp[(size_t)n*256];       p1 += zp[(size_t)(n+1)*256];
        p2 += zp[(size_t)(n+2)*256];   p3 += zp[(size_t)(n+3)*256];
    }
    for (; n < 394; ++n) p0 += zp[(size_t)n*256];
    float pooled = (p0+p1+p2+p3) * (1.f/394.f);
    float a = pooled, sq = pooled*pooled;
    #pragma unroll
    for (int m = 1; m < 64; m <<= 1) { a += __shfl_xor(a, m); sq += __shfl_xor(sq, m); }
    if (lane == 0) { red[wave] = a; red[4+wave] = sq; }
    __syncthreads();
    float tot = red[0]+red[1]+red[2]+red[3];
    float totq = red[4]+red[5]+red[6]+red[7];
    float mean = tot*(1.f/256.f);
    float rs = rsqrtf(totq*(1.f/256.f) - mean*mean + 1e-5f);
    float ln = (pooled-mean)*rs*lg[e] + lb[e];
    float t0 = ln * wc[e*2], t1 = ln * wc[e*2+1];
    #pragma unroll
    for (int m = 1; m < 64; m <<= 1) { t0 += __shfl_xor(t0, m); t1 += __shfl_xor(t1, m); }
    __syncthreads();
    if (lane == 0) { red[wave] = t0; red[4+wave] = t1; }
    __syncthreads();
    if (e < 2) {
        float l0 = red[0]+red[1]+red[2]+red[3] + bc[0];
        float l1 = red[4]+red[5]+red[6]+red[7] + bc[1];
        float mx = fmaxf(l0, l1);
        float lse = mx + logf(__expf(l0-mx) + __expf(l1-mx));
        out[b*2 + e] = (e == 0 ? l0 : l1) - lse;
    }
}

extern "C" void kernel_launch(void* const* d_in, const int* in_sizes, int n_in,
                              void* d_out, int out_size, void* d_ws, size_t ws_size,
                              hipStream_t stream) {
    const float* x    = (const float*)d_in[0];
    const float* W1   = (const float*)d_in[1];
    const float* b1   = (const float*)d_in[2];
    const float* cls1 = (const float*)d_in[3];
    const float* W2   = (const float*)d_in[4];
    const float* b2   = (const float*)d_in[5];
    const float* cls2 = (const float*)d_in[6];
    const float* ln1g = (const float*)d_in[7];
    const float* ln1b = (const float*)d_in[8];
    const float* Wq   = (const float*)d_in[9];
    const float* bq   = (const float*)d_in[10];
    const float* Wk   = (const float*)d_in[11];
    const float* bk   = (const float*)d_in[12];
    const float* Wv   = (const float*)d_in[13];
    const float* bv   = (const float*)d_in[14];
    const float* Wp   = (const float*)d_in[15];
    const float* bp   = (const float*)d_in[16];
    const float* ln2g = (const float*)d_in[17];
    const float* ln2b = (const float*)d_in[18];
    const float* lncg = (const float*)d_in[19];
    const float* lncb = (const float*)d_in[20];
    const float* Wc   = (const float*)d_in[21];
    const float* bcp  = (const float*)d_in[22];

    int Bn = in_sizes[0] / (3*224*224);

    // ws: [weights 1,015,808 B][per-img: z 403456 | h/o 201728 | q 212992 | kb 212992 | vt 212992]
    const size_t WBYTES = 1015808;
    const size_t PER_IMG = 403456 + 201728 + 212992*3;   // 1,244,160 B
    size_t avail = (ws_size > WBYTES) ? ws_size - WBYTES : 0;
    int Bc = (int)(avail / PER_IMG);
    if (Bc < 1) Bc = 1;
    if (Bc > Bn) Bc = Bn;

    u16* w1t = (u16*)d_ws;            // [256][768]
    u16* w2t = w1t + 196608;          // [256][192]
    u16* wqt = w2t + 49152;           // [256][256] x4
    u16* wkt = wqt + 65536;
    u16* wvt = wkt + 65536;
    u16* wpt = wvt + 65536;
    float* z = (float*)(wpt + 65536);               // [Bc][394][256] f32
    u16* h   = (u16*)(z + (size_t)Bc*100864);       // [Bc][394][256]  (aliased as o)
    u16* o   = h;
    u16* q   = h + (size_t)Bc*100864;               // [Bc*2][416][128]
    u16* kb  = q + (size_t)Bc*106496;
    u16* vt  = kb + (size_t)Bc*106496;              // [Bc*2][128][416]

    k_wtrans<<<1984, 256, 0, stream>>>(W1, W2, Wq, Wk, Wv, Wp, w1t, w2t, wqt, wkt, wvt, wpt);

    for (int b0 = 0; b0 < Bn; b0 += Bc) {
        int bc = (Bn - b0 < Bc) ? (Bn - b0) : Bc;
        const float* xb = x + (size_t)b0 * 3*224*224;
        float* outb = (float*)d_out + (size_t)b0 * 2;

        k_cls<<<bc, 256, 0, stream>>>(cls1, cls2, ln1g, ln1b, z, h);
        k_embed1<<<dim3(13, bc), 256, 0, stream>>>(xb, w1t, b1, ln1g, ln1b, z, h);
        k_embed2<<<dim3(13, bc), 256, 0, stream>>>(xb, w2t, b2, ln1g, ln1b, z, h);
        k_qkv<<<dim3(13, bc), 256, 0, stream>>>(h, wqt, wkt, wvt, bq, bk, bv, q, kb, vt);
        k_att<<<dim3(7, bc*2), 256, 0, stream>>>(q, kb, vt, o);
        k_proj<<<dim3(13, bc), 256, 0, stream>>>(o, wpt, bp, ln2g, ln2b, z);
        k_pool<<<bc, 256, 0, stream>>>(z, lncg, lncb, Wc, bcp, outb);
    }
}

// Round 8
// 570.172 us; speedup vs baseline: 1.3683x; 1.0027x over previous
//
#include <hip/hip_runtime.h>

typedef short short8 __attribute__((ext_vector_type(8)));
typedef float f32x4 __attribute__((ext_vector_type(4)));
typedef unsigned short us4 __attribute__((ext_vector_type(4)));
typedef unsigned short u16;

#define MFMA(a,b,c) __builtin_amdgcn_mfma_f32_16x16x32_bf16((a),(b),(c),0,0,0)

__device__ __forceinline__ u16 f2b(float f) {
    union { float f; unsigned int i; } v; v.f = f;
    unsigned int x = v.i;
    return (u16)((x + 0x7fffu + ((x >> 16) & 1u)) >> 16);
}

// ---- all weights -> bf16 transposed; W1/W2 additionally permuted to channel-planar k' ----
// W1: k = pi*48+pj*3+c  ->  k' = c*256+pi*16+pj      W2: k = pi*24+pj*3+c -> k' = c*64+pi*8+pj
__global__ __launch_bounds__(256) void k_wtrans(const float* __restrict__ W1,
        const float* __restrict__ W2, const float* __restrict__ Wq, const float* __restrict__ Wk,
        const float* __restrict__ Wv, const float* __restrict__ Wp,
        u16* __restrict__ w1t, u16* __restrict__ w2t, u16* __restrict__ wqt,
        u16* __restrict__ wkt, u16* __restrict__ wvt, u16* __restrict__ wpt) {
    int bx = blockIdx.x, n = threadIdx.x;
    if (bx < 768) {
        int k = bx, c = k % 3, t = k / 3, pj = t & 15, pi = t >> 4;
        w1t[(size_t)n*768 + c*256 + pi*16 + pj] = f2b(W1[(size_t)k*256 + n]);
    } else if (bx < 960) {
        int k = bx - 768, c = k % 3, t = k / 3, pj = t & 7, pi = t >> 3;
        w2t[(size_t)n*192 + c*64 + pi*8 + pj] = f2b(W2[(size_t)k*256 + n]);
    } else if (bx < 1216) { int k = bx - 960;  wqt[(size_t)n*256 + k] = f2b(Wq[(size_t)k*256 + n]); }
    else if (bx < 1472)   { int k = bx - 1216; wkt[(size_t)n*256 + k] = f2b(Wk[(size_t)k*256 + n]); }
    else if (bx < 1728)   { int k = bx - 1472; wvt[(size_t)n*256 + k] = f2b(Wv[(size_t)k*256 + n]); }
    else                  { int k = bx - 1728; wpt[(size_t)n*256 + k] = f2b(Wp[(size_t)k*256 + n]); }
}

// ---- cls tokens (0 = cls2, 197 = cls1) into z, fused LN1 -> h ----
__global__ __launch_bounds__(256) void k_cls(const float* __restrict__ cls1,
        const float* __restrict__ cls2, const float* __restrict__ g1, const float* __restrict__ be1,
        float* __restrict__ z, u16* __restrict__ h) {
    __shared__ float red[16];
    int b = blockIdx.x, e = threadIdx.x, lane = e & 63, w = e >> 6;
    float v0 = cls2[e], v1 = cls1[e];
    z[((size_t)b*394 + 0)*256 + e]   = v0;
    z[((size_t)b*394 + 197)*256 + e] = v1;
    float s0 = v0, q0 = v0*v0, s1 = v1, q1 = v1*v1;
    #pragma unroll
    for (int m = 1; m < 64; m <<= 1) {
        s0 += __shfl_xor(s0, m); q0 += __shfl_xor(q0, m);
        s1 += __shfl_xor(s1, m); q1 += __shfl_xor(q1, m);
    }
    if (lane == 0) { red[w] = s0; red[4+w] = q0; red[8+w] = s1; red[12+w] = q1; }
    __syncthreads();
    float S0 = red[0]+red[1]+red[2]+red[3],   Q0 = red[4]+red[5]+red[6]+red[7];
    float S1 = red[8]+red[9]+red[10]+red[11], Q1 = red[12]+red[13]+red[14]+red[15];
    float m0 = S0*(1.f/256.f), r0 = rsqrtf(Q0*(1.f/256.f) - m0*m0 + 1e-5f);
    float m1 = S1*(1.f/256.f), r1 = rsqrtf(Q1*(1.f/256.f) - m1*m1 + 1e-5f);
    h[((size_t)b*394 + 0)*256 + e]   = f2b((v0-m0)*r0*g1[e] + be1[e]);
    h[((size_t)b*394 + 197)*256 + e] = f2b((v1-m1)*r1*g1[e] + be1[e]);
}

// ---- patch embed P=16 (tokens 198..393) + fused LN1 ----
__global__ __launch_bounds__(256) void k_embed1(const float* __restrict__ x,
        const u16* __restrict__ w1t, const float* __restrict__ b1,
        const float* __restrict__ g1, const float* __restrict__ be1,
        float* __restrict__ z, u16* __restrict__ h) {
    __shared__ __align__(16) u16 A[16*776];
    __shared__ __align__(16) float S[16*260];
    int b = blockIdx.y, g = blockIdx.x, tid = threadIdx.x;
    int p = tid >> 4, pi = tid & 15;
    int j = g*16 + p;
    if (j < 196) {
        int hi = j / 14, wi = j - hi*14;
        #pragma unroll
        for (int c = 0; c < 3; ++c) {
            const float* src = x + (((size_t)b*3 + c)*224 + hi*16 + pi)*224 + wi*16;
            #pragma unroll
            for (int s4 = 0; s4 < 4; ++s4) {
                f32x4 r = *(const f32x4*)(src + s4*4);
                us4 o; o[0] = f2b(r[0]); o[1] = f2b(r[1]); o[2] = f2b(r[2]); o[3] = f2b(r[3]);
                *(us4*)&A[p*776 + c*256 + pi*16 + s4*4] = o;
            }
        }
    } else {
        us4 zer = {0,0,0,0};
        #pragma unroll
        for (int c = 0; c < 3; ++c)
            #pragma unroll
            for (int s4 = 0; s4 < 4; ++s4)
                *(us4*)&A[p*776 + c*256 + pi*16 + s4*4] = zer;
    }
    __syncthreads();
    int w = tid >> 6, lane = tid & 63, quad = lane >> 4, tf = lane & 15;
    f32x4 zero = {0.f,0.f,0.f,0.f};
    f32x4 acc[4] = {zero,zero,zero,zero};
    for (int ks = 0; ks < 24; ++ks) {
        short8 a = *(const short8*)&A[tf*776 + ks*32 + quad*8];
        #pragma unroll
        for (int nf = 0; nf < 4; ++nf) {
            int n = w*64 + nf*16 + tf;
            short8 bb = *(const short8*)&w1t[(size_t)n*768 + ks*32 + quad*8];
            acc[nf] = MFMA(a, bb, acc[nf]);
        }
    }
    #pragma unroll
    for (int nf = 0; nf < 4; ++nf) {
        int n = w*64 + nf*16 + tf;
        float bias = b1[n];
        #pragma unroll
        for (int i = 0; i < 4; ++i)
            S[(quad*4 + i)*260 + n] = acc[nf][i] + bias;
    }
    __syncthreads();
    #pragma unroll
    for (int rr = 0; rr < 4; ++rr) {
        int row = w*4 + rr;
        int j2 = g*16 + row;
        f32x4 v = *(const f32x4*)&S[row*260 + lane*4];
        float s = v[0]+v[1]+v[2]+v[3];
        float sq = v[0]*v[0]+v[1]*v[1]+v[2]*v[2]+v[3]*v[3];
        #pragma unroll
        for (int m = 1; m < 64; m <<= 1) { s += __shfl_xor(s, m); sq += __shfl_xor(sq, m); }
        float mean = s*(1.f/256.f);
        float rs = rsqrtf(sq*(1.f/256.f) - mean*mean + 1e-5f);
        if (j2 < 196) {
            size_t base = ((size_t)b*394 + 198 + j2)*256 + lane*4;
            *(f32x4*)&z[base] = v;
            us4 ho;
            #pragma unroll
            for (int c = 0; c < 4; ++c) {
                int e = lane*4 + c;
                ho[c] = f2b((v[c]-mean)*rs*g1[e] + be1[e]);
            }
            *(us4*)&h[base] = ho;
        }
    }
}

// ---- patch embed P=8 sampled (tokens 1..196, patch=4*it-1) + fused LN1 ----
__global__ __launch_bounds__(256) void k_embed2(const float* __restrict__ x,
        const u16* __restrict__ w2t, const float* __restrict__ b2,
        const float* __restrict__ g1, const float* __restrict__ be1,
        float* __restrict__ z, u16* __restrict__ h) {
    __shared__ __align__(16) u16 A[16*200];
    __shared__ __align__(16) float S[16*260];
    int b = blockIdx.y, g = blockIdx.x, tid = threadIdx.x;
    int p = tid >> 4, s16 = tid & 15;
    int pi = s16 >> 1, ph = s16 & 1;
    int it = g*16 + p + 1;
    if (it <= 196) {
        int patch = 4*it - 1;
        int hi = patch / 28, wi = patch - hi*28;
        #pragma unroll
        for (int c = 0; c < 3; ++c) {
            const float* src = x + (((size_t)b*3 + c)*224 + hi*8 + pi)*224 + wi*8 + ph*4;
            f32x4 r = *(const f32x4*)src;
            us4 o; o[0] = f2b(r[0]); o[1] = f2b(r[1]); o[2] = f2b(r[2]); o[3] = f2b(r[3]);
            *(us4*)&A[p*200 + c*64 + pi*8 + ph*4] = o;
        }
    } else {
        us4 zer = {0,0,0,0};
        #pragma unroll
        for (int c = 0; c < 3; ++c)
            *(us4*)&A[p*200 + c*64 + pi*8 + ph*4] = zer;
    }
    __syncthreads();
    int w = tid >> 6, lane = tid & 63, quad = lane >> 4, tf = lane & 15;
    f32x4 zero = {0.f,0.f,0.f,0.f};
    f32x4 acc[4] = {zero,zero,zero,zero};
    for (int ks = 0; ks < 6; ++ks) {
        short8 a = *(const short8*)&A[tf*200 + ks*32 + quad*8];
        #pragma unroll
        for (int nf = 0; nf < 4; ++nf) {
            int n = w*64 + nf*16 + tf;
            short8 bb = *(const short8*)&w2t[(size_t)n*192 + ks*32 + quad*8];
            acc[nf] = MFMA(a, bb, acc[nf]);
        }
    }
    #pragma unroll
    for (int nf = 0; nf < 4; ++nf) {
        int n = w*64 + nf*16 + tf;
        float bias = b2[n];
        #pragma unroll
        for (int i = 0; i < 4; ++i)
            S[(quad*4 + i)*260 + n] = acc[nf][i] + bias;
    }
    __syncthreads();
    #pragma unroll
    for (int rr = 0; rr < 4; ++rr) {
        int row = w*4 + rr;
        int it2 = g*16 + row + 1;
        f32x4 v = *(const f32x4*)&S[row*260 + lane*4];
        float s = v[0]+v[1]+v[2]+v[3];
        float sq = v[0]*v[0]+v[1]*v[1]+v[2]*v[2]+v[3]*v[3];
        #pragma unroll
        for (int m = 1; m < 64; m <<= 1) { s += __shfl_xor(s, m); sq += __shfl_xor(sq, m); }
        float mean = s*(1.f/256.f);
        float rs = rsqrtf(sq*(1.f/256.f) - mean*mean + 1e-5f);
        if (it2 <= 196) {
            size_t base = ((size_t)b*394 + it2)*256 + lane*4;
            *(f32x4*)&z[base] = v;
            us4 ho;
            #pragma unroll
            for (int c = 0; c < 4; ++c) {
                int e = lane*4 + c;
                ho[c] = f2b((v[c]-mean)*rs*g1[e] + be1[e]);
            }
            *(us4*)&h[base] = ho;
        }
    }
}

// ---- QKV GEMM, split by output (z-dim), M=32: q,k -> [bh][416][128]; v -> vt [bh][128][416] ----
// all pad rows/cols (n>=394) written as zeros.
__global__ __launch_bounds__(256) void k_qkv(const u16* __restrict__ h,
        const u16* __restrict__ wqt, const u16* __restrict__ wkt, const u16* __restrict__ wvt,
        const float* __restrict__ bq, const float* __restrict__ bk, const float* __restrict__ bv,
        u16* __restrict__ q, u16* __restrict__ kb, u16* __restrict__ vt) {
    __shared__ __align__(16) u16 A[32*264];
    int mt = blockIdx.x, b = blockIdx.y, wsel = blockIdx.z, tid = threadIdx.x;
    const u16* wt = (wsel==0) ? wqt : (wsel==1) ? wkt : wvt;
    const float* bs = (wsel==0) ? bq : (wsel==1) ? bk : bv;
    for (int idx = tid; idx < 2048; idx += 256) {
        int row = idx >> 6, col4 = (idx & 63) * 4;
        int n = mt*32 + row;
        us4 val = {0,0,0,0};
        if (n < 394) val = *(const us4*)&h[((size_t)b*394 + n)*256 + col4];
        *(us4*)&A[row*264 + col4] = val;
    }
    __syncthreads();
    int w = tid >> 6, lane = tid & 63, quad = lane >> 4, tf = lane & 15;
    f32x4 zero = {0.f,0.f,0.f,0.f};
    f32x4 acc[2][4];
    #pragma unroll
    for (int m = 0; m < 2; ++m)
        #pragma unroll
        for (int nf = 0; nf < 4; ++nf) acc[m][nf] = zero;
    for (int ks = 0; ks < 8; ++ks) {
        short8 a0 = *(const short8*)&A[tf*264 + ks*32 + quad*8];
        short8 a1 = *(const short8*)&A[(16+tf)*264 + ks*32 + quad*8];
        #pragma unroll
        for (int nf = 0; nf < 4; ++nf) {
            short8 bb = *(const short8*)&wt[(size_t)(w*64 + nf*16 + tf)*256 + ks*32 + quad*8];
            acc[0][nf] = MFMA(a0, bb, acc[0][nf]);
            acc[1][nf] = MFMA(a1, bb, acc[1][nf]);
        }
    }
    #pragma unroll
    for (int nf = 0; nf < 4; ++nf) {
        int e = w*64 + nf*16 + tf;
        int hh = e >> 7, d = e & 127;
        size_t bh = (size_t)b*2 + hh;
        float bsv = bs[e];
        #pragma unroll
        for (int m = 0; m < 2; ++m)
            #pragma unroll
            for (int i = 0; i < 4; ++i) {
                int n = mt*32 + m*16 + quad*4 + i;
                u16 val = (n < 394) ? f2b(acc[m][nf][i] + bsv) : (u16)0;
                if (wsel == 0)      q [(bh*416 + n)*128 + d] = val;
                else if (wsel == 1) kb[(bh*416 + n)*128 + d] = val;
                else                vt[(bh*128 + d)*416 + n] = val;
            }
    }
}

// ---- attention: 4 waves/block, 64 q-rows, LDS-shared K/V tiles ----
__global__ __launch_bounds__(256) void k_att(const u16* __restrict__ q,
        const u16* __restrict__ kbuf, const u16* __restrict__ vt, u16* __restrict__ o) {
    __shared__ __align__(16) u16 Pl[4*16*424];   // 54,272 B
    __shared__ __align__(16) u16 Stage[5120];    // 10,240 B (K: 32x136, V: 128x40)
    int bx = blockIdx.x, bh = blockIdx.y, tid = threadIdx.x;
    int w = tid >> 6, lane = tid & 63, quad = lane >> 4, tf = lane & 15;
    int mt_raw = bx*4 + w;
    int mt = mt_raw < 26 ? mt_raw : 25;
    const u16* qp = q    + (size_t)bh*53248;
    const u16* kp = kbuf + (size_t)bh*53248;
    const u16* vp = vt   + (size_t)bh*53248;
    short8 afr[4];
    #pragma unroll
    for (int ks = 0; ks < 4; ++ks)
        afr[ks] = *(const short8*)&qp[(size_t)(mt*16 + tf)*128 + ks*32 + quad*8];
    f32x4 zero = {0.f,0.f,0.f,0.f};
    f32x4 acc[26];
    #pragma unroll
    for (int nt = 0; nt < 26; ++nt) acc[nt] = zero;
    // phase 1: QK^T over 13 K-chunks of 32 rows (K chunk: 32 rows x 128, stride 136)
    for (int kc = 0; kc < 13; ++kc) {
        for (int i = tid; i < 512; i += 256) {
            int r = i >> 4, seg = i & 15;
            uint4 vsrc = *(const uint4*)&kp[(size_t)(kc*32 + r)*128 + seg*8];
            *(uint4*)&Stage[r*136 + seg*8] = vsrc;
        }
        __syncthreads();
        #pragma unroll
        for (int ncl = 0; ncl < 2; ++ncl) {
            int nt = kc*2 + ncl;
            #pragma unroll
            for (int ks = 0; ks < 4; ++ks) {
                short8 bb = *(const short8*)&Stage[(ncl*16 + tf)*136 + ks*32 + quad*8];
                acc[nt] = MFMA(afr[ks], bb, acc[nt]);
            }
        }
        __syncthreads();
    }
    // phase 2: softmax (valid cols: nt<24 fully, nt==24 tf<10)
    u16* myP = Pl + w*16*424;
    #pragma unroll
    for (int i = 0; i < 4; ++i) {
        int row = quad*4 + i;
        float mx = -3e38f;
        #pragma unroll
        for (int nt = 0; nt < 26; ++nt)
            if (nt < 24 || (nt == 24 && tf < 10)) mx = fmaxf(mx, acc[nt][i]);
        #pragma unroll
        for (int m = 1; m < 16; m <<= 1) mx = fmaxf(mx, __shfl_xor(mx, m));
        float s = 0.f;
        #pragma unroll
        for (int nt = 0; nt < 26; ++nt)
            if (nt < 24 || (nt == 24 && tf < 10)) s += __expf(acc[nt][i] - mx);
        #pragma unroll
        for (int m = 1; m < 16; m <<= 1) s += __shfl_xor(s, m);
        float inv = 1.f / (16.f * s);
        #pragma unroll
        for (int nt = 0; nt < 26; ++nt) {
            float p = (nt < 24 || (nt == 24 && tf < 10)) ? __expf(acc[nt][i] - mx) * inv : 0.f;
            myP[row*424 + nt*16 + tf] = f2b(p);
        }
    }
    __syncthreads();
    // phase 3: PV over 13 V-chunks of 32 cols (V chunk: 128 rows(d) x 32, stride 40)
    f32x4 acc2[8];
    #pragma unroll
    for (int nf = 0; nf < 8; ++nf) acc2[nf] = zero;
    for (int kc = 0; kc < 13; ++kc) {
        for (int i = tid; i < 512; i += 256) {
            int d = i >> 2, seg = i & 3;                 // 128 rows x 4 segs of 8 u16
            uint4 vsrc = *(const uint4*)&vp[(size_t)d*416 + kc*32 + seg*8];
            *(uint4*)&Stage[d*40 + seg*8] = vsrc;
        }
        __syncthreads();
        short8 a = *(const short8*)&myP[tf*424 + kc*32 + quad*8];
        #pragma unroll
        for (int nf = 0; nf < 8; ++nf) {
            short8 bb = *(const short8*)&Stage[(nf*16 + tf)*40 + quad*8];
            acc2[nf] = MFMA(a, bb, acc2[nf]);
        }
        __syncthreads();
    }
    int b = bh >> 1, hh = bh & 1;
    if (mt_raw < 26) {
        #pragma unroll
        for (int nf = 0; nf < 8; ++nf) {
            int e = hh*128 + nf*16 + tf;
            #pragma unroll
            for (int i = 0; i < 4; ++i) {
                int n = mt_raw*16 + quad*4 + i;
                if (n < 394)
                    o[((size_t)b*394 + n)*256 + e] = f2b(acc2[nf][i]);
            }
        }
    }
}

// ---- proj GEMM (M=32) + LN2 + residual into z ----
__global__ __launch_bounds__(256) void k_proj(const u16* __restrict__ o,
        const u16* __restrict__ wpt, const float* __restrict__ bp,
        const float* __restrict__ g2, const float* __restrict__ bb2,
        float* __restrict__ z) {
    __shared__ __align__(16) u16 A[32*264];
    __shared__ __align__(16) float S[32*260];
    int mt = blockIdx.x, b = blockIdx.y, tid = threadIdx.x;
    int w = tid >> 6, lane = tid & 63, quad = lane >> 4, tf = lane & 15;
    for (int idx = tid; idx < 2048; idx += 256) {
        int row = idx >> 6, col4 = (idx & 63) * 4;
        int n = mt*32 + row;
        us4 val = {0,0,0,0};
        if (n < 394) val = *(const us4*)&o[((size_t)b*394 + n)*256 + col4];
        *(us4*)&A[row*264 + col4] = val;
    }
    __syncthreads();
    f32x4 zero = {0.f,0.f,0.f,0.f};
    f32x4 acc[2][4];
    #pragma unroll
    for (int m = 0; m < 2; ++m)
        #pragma unroll
        for (int nf = 0; nf < 4; ++nf) acc[m][nf] = zero;
    for (int ks = 0; ks < 8; ++ks) {
        short8 a0 = *(const short8*)&A[tf*264 + ks*32 + quad*8];
        short8 a1 = *(const short8*)&A[(16+tf)*264 + ks*32 + quad*8];
        #pragma unroll
        for (int nf = 0; nf < 4; ++nf) {
            short8 bb = *(const short8*)&wpt[(size_t)(w*64 + nf*16 + tf)*256 + ks*32 + quad*8];
            acc[0][nf] = MFMA(a0, bb, acc[0][nf]);
            acc[1][nf] = MFMA(a1, bb, acc[1][nf]);
        }
    }
    #pragma unroll
    for (int nf = 0; nf < 4; ++nf) {
        int e = w*64 + nf*16 + tf;
        float bsv = bp[e];
        #pragma unroll
        for (int m = 0; m < 2; ++m)
            #pragma unroll
            for (int i = 0; i < 4; ++i)
                S[(m*16 + quad*4 + i)*260 + e] = acc[m][nf][i] + bsv;
    }
    __syncthreads();
    #pragma unroll
    for (int rr = 0; rr < 8; ++rr) {
        int row = w*8 + rr;
        f32x4 v = *(const f32x4*)&S[row*260 + lane*4];
        float s = v[0]+v[1]+v[2]+v[3];
        float sq = v[0]*v[0]+v[1]*v[1]+v[2]*v[2]+v[3]*v[3];
        #pragma unroll
        for (int m = 1; m < 64; m <<= 1) { s += __shfl_xor(s, m); sq += __shfl_xor(sq, m); }
        float mean = s*(1.f/256.f);
        float rs = rsqrtf(sq*(1.f/256.f) - mean*mean + 1e-5f);
        int n = mt*32 + row;
        if (n < 394) {
            float* zr = z + ((size_t)b*394 + n)*256 + lane*4;
            f32x4 zv = *(f32x4*)zr;
            #pragma unroll
            for (int c = 0; c < 4; ++c) {
                int e = lane*4 + c;
                zv[c] += (v[c]-mean)*rs*g2[e] + bb2[e];
            }
            *(f32x4*)zr = zv;
        }
    }
}

// ---- mean-pool + LNc + classifier + log_softmax (f32 out) ----
__global__ __launch_bounds__(256) void k_pool(const float* __restrict__ z,
        const float* __restrict__ lg, const float* __restrict__ lb,
        const float* __restrict__ wc, const float* __restrict__ bc,
        float* __restrict__ out) {
    __shared__ float red[8];
    int b = blockIdx.x, e = threadIdx.x;
    int wave = e >> 6, lane = e & 63;
    const float* zp = z + (size_t)b*394*256 + e;
    float p0 = 0.f, p1 = 0.f, p2 = 0.f, p3 = 0.f;
    int n = 0;
    for (; n + 3 < 394; n += 4) {
        p0 += zp[(size_t)n*256];       p1 += zp[(size_t)(n+1)*256];
        p2 += zp[(size_t)(n+2)*256];   p3 += zp[(size_t)(n+3)*256];
    }
    for (; n < 394; ++n) p0 += zp[(size_t)n*256];
    float pooled = (p0+p1+p2+p3) * (1.f/394.f);
    float a = pooled, sq = pooled*pooled;
    #pragma unroll
    for (int m = 1; m < 64; m <<= 1) { a += __shfl_xor(a, m); sq += __shfl_xor(sq, m); }
    if (lane == 0) { red[wave] = a; red[4+wave] = sq; }
    __syncthreads();
    float tot = red[0]+red[1]+red[2]+red[3];
    float totq = red[4]+red[5]+red[6]+red[7];
    float mean = tot*(1.f/256.f);
    float rs = rsqrtf(totq*(1.f/256.f) - mean*mean + 1e-5f);
    float ln = (pooled-mean)*rs*lg[e] + lb[e];
    float t0 = ln * wc[e*2], t1 = ln * wc[e*2+1];
    #pragma unroll
    for (int m = 1; m < 64; m <<= 1) { t0 += __shfl_xor(t0, m); t1 += __shfl_xor(t1, m); }
    __syncthreads();
    if (lane == 0) { red[wave] = t0; red[4+wave] = t1; }
    __syncthreads();
    if (e < 2) {
        float l0 = red[0]+red[1]+red[2]+red[3] + bc[0];
        float l1 = red[4]+red[5]+red[6]+red[7] + bc[1];
        float mx = fmaxf(l0, l1);
        float lse = mx + logf(__expf(l0-mx) + __expf(l1-mx));
        out[b*2 + e] = (e == 0 ? l0 : l1) - lse;
    }
}

extern "C" void kernel_launch(void* const* d_in, const int* in_sizes, int n_in,
                              void* d_out, int out_size, void* d_ws, size_t ws_size,
                              hipStream_t stream) {
    const float* x    = (const float*)d_in[0];
    const float* W1   = (const float*)d_in[1];
    const float* b1   = (const float*)d_in[2];
    const float* cls1 = (const float*)d_in[3];
    const float* W2   = (const float*)d_in[4];
    const float* b2   = (const float*)d_in[5];
    const float* cls2 = (const float*)d_in[6];
    const float* ln1g = (const float*)d_in[7];
    const float* ln1b = (const float*)d_in[8];
    const float* Wq   = (const float*)d_in[9];
    const float* bq   = (const float*)d_in[10];
    const float* Wk   = (const float*)d_in[11];
    const float* bk   = (const float*)d_in[12];
    const float* Wv   = (const float*)d_in[13];
    const float* bv   = (const float*)d_in[14];
    const float* Wp   = (const float*)d_in[15];
    const float* bp   = (const float*)d_in[16];
    const float* ln2g = (const float*)d_in[17];
    const float* ln2b = (const float*)d_in[18];
    const float* lncg = (const float*)d_in[19];
    const float* lncb = (const float*)d_in[20];
    const float* Wc   = (const float*)d_in[21];
    const float* bcp  = (const float*)d_in[22];

    int Bn = in_sizes[0] / (3*224*224);

    // ws: [weights 1,015,808 B][per-img: z 403456 | h/o 201728 | q 212992 | kb 212992 | vt 212992]
    const size_t WBYTES = 1015808;
    const size_t PER_IMG = 403456 + 201728 + 212992*3;   // 1,244,160 B
    size_t avail = (ws_size > WBYTES) ? ws_size - WBYTES : 0;
    int Bc = (int)(avail / PER_IMG);
    if (Bc < 1) Bc = 1;
    if (Bc > Bn) Bc = Bn;

    u16* w1t = (u16*)d_ws;            // [256][768]
    u16* w2t = w1t + 196608;          // [256][192]
    u16* wqt = w2t + 49152;           // [256][256] x4
    u16* wkt = wqt + 65536;
    u16* wvt = wkt + 65536;
    u16* wpt = wvt + 65536;
    float* z = (float*)(wpt + 65536);               // [Bc][394][256] f32
    u16* h   = (u16*)(z + (size_t)Bc*100864);       // [Bc][394][256]  (aliased as o)
    u16* o   = h;
    u16* q   = h + (size_t)Bc*100864;               // [Bc*2][416][128]
    u16* kb  = q + (size_t)Bc*106496;
    u16* vt  = kb + (size_t)Bc*106496;              // [Bc*2][128][416]

    k_wtrans<<<1984, 256, 0, stream>>>(W1, W2, Wq, Wk, Wv, Wp, w1t, w2t, wqt, wkt, wvt, wpt);

    for (int b0 = 0; b0 < Bn; b0 += Bc) {
        int bc = (Bn - b0 < Bc) ? (Bn - b0) : Bc;
        const float* xb = x + (size_t)b0 * 3*224*224;
        float* outb = (float*)d_out + (size_t)b0 * 2;

        k_cls<<<bc, 256, 0, stream>>>(cls1, cls2, ln1g, ln1b, z, h);
        k_embed1<<<dim3(13, bc), 256, 0, stream>>>(xb, w1t, b1, ln1g, ln1b, z, h);
        k_embed2<<<dim3(13, bc), 256, 0, stream>>>(xb, w2t, b2, ln1g, ln1b, z, h);
        k_qkv<<<dim3(13, bc, 3), 256, 0, stream>>>(h, wqt, wkt, wvt, bq, bk, bv, q, kb, vt);
        k_att<<<dim3(7, bc*2), 256, 0, stream>>>(q, kb, vt, o);
        k_proj<<<dim3(13, bc), 256, 0, stream>>>(o, wpt, bp, ln2g, ln2b, z);
        k_pool<<<bc, 256, 0, stream>>>(z, lncg, lncb, Wc, bcp, outb);
    }
}